// Round 8
// baseline (815.798 us; speedup 1.0000x reference)
//
#include <hip/hip_runtime.h>
#include <hip/hip_bf16.h>

// VectorQuantize: argmin_k ||x - e_k||^2 then gather values[k].
// R8: register-staged GEMM (T14): global_load -> VGPR -> ds_write_b128,
// replacing global_load_lds entirely (R2-R7 showed the gload_lds staging
// path pinned at ~3 B/cyc/CU regardless of structure; reg-staging is the
// HK/m249-proven alternative). Tile 256 rows x 128 codes, BK=64, 8 waves
// (4M x 2N), 2-phase dbuf, one barrier/step. Epilogue: per-row top-2 keys
// per 64-code strip -> global top-4 -> exact f32 rescore (np tie semantics)
// -> gather values[best].
//
// Pack layouts (granule = 8 bf16 = 16 B):
//   Apack[64 tiles][k16 0..63][row 0..255][8]  (prep256)  A slab/step: 2048 g
//   Bpack[64 tiles][k16 0..63][row 0..127][8]  (prep128)  B slab/step: 1024 g
// K-step t uses granules t*2048+g (A) / t*1024+g (B); LDS granule index == g.

#define D      512
#define M      16384
#define NCODE  8192
#define NSTEP  8           // K=512 / BK=64
#define ATILEG 131072      // elems per A tile (256*512)
#define BTILEG 65536       // elems per B tile (128*512)

typedef float f32x4  __attribute__((ext_vector_type(4)));
typedef short bf16x8 __attribute__((ext_vector_type(8)));

#define KMAX 0xFFFFFFFFFFFFFFFFull

__device__ __forceinline__ unsigned long long score_key(float sc, int code) {
  unsigned int u = __float_as_uint(sc);
  unsigned int su = u ^ ((unsigned int)((int)u >> 31) | 0x80000000u);
  return ((unsigned long long)su << 32) | (unsigned int)code;
}

__device__ __forceinline__ void kins2(unsigned long long k,
                                      unsigned long long& k1, unsigned long long& k2) {
  if (k < k1) { k2 = k1; k1 = k; }
  else if (k < k2) { k2 = k; }
}

__device__ __forceinline__ void kins4(unsigned long long k,
    unsigned long long& k0, unsigned long long& k1,
    unsigned long long& k2, unsigned long long& k3) {
  if (k < k0)      { k3 = k2; k2 = k1; k1 = k0; k0 = k; }
  else if (k < k1) { k3 = k2; k2 = k1; k1 = k; }
  else if (k < k2) { k3 = k2; k2 = k; }
  else if (k < k3) { k3 = k; }
}

// ---- 1a. f32 -> hi-bf16 256-row tile-transposed pack ------------------------
__global__ __launch_bounds__(256)
void prep256(const float* __restrict__ src, __hip_bfloat16* __restrict__ dst) {
  __shared__ __hip_bfloat16 tile[256][72];
  const int tid = threadIdx.x;
  const int c = blockIdx.x & 7, t = blockIdx.x >> 3;
  const float* srow = src + (size_t)t * 256 * D;
  __hip_bfloat16* dbase = dst + (size_t)t * ATILEG;

#pragma unroll
  for (int j = 0; j < 8; ++j) {
    int f = tid + j * 256;                 // row = f>>3, k16l = f&7
    int row = f >> 3, k16l = f & 7;
    const float4* p = (const float4*)(srow + (size_t)row * D + c * 64 + k16l * 8);
    float4 v0 = p[0], v1 = p[1];
    float vv[8] = {v0.x, v0.y, v0.z, v0.w, v1.x, v1.y, v1.z, v1.w};
    union { bf16x8 v; unsigned short u[8]; } pk;
#pragma unroll
    for (int e = 0; e < 8; ++e) {
      __hip_bfloat16 h = __float2bfloat16(vv[e]);   // RNE
      pk.u[e] = *(unsigned short*)&h;
    }
    *(bf16x8*)&tile[row][k16l * 8] = pk.v;
  }
  __syncthreads();
#pragma unroll
  for (int j = 0; j < 8; ++j) {
    int g = tid + j * 256;                 // row = g&255, k16l = g>>8
    int row = g & 255, k16l = g >> 8;
    bf16x8 v = *(const bf16x8*)&tile[row][k16l * 8];
    *(bf16x8*)(dbase + ((size_t)(c * 8 + k16l) * 256 + row) * 8) = v;
  }
}

// ---- 1b. f32 -> hi-bf16 128-row tile-transposed pack ------------------------
__global__ __launch_bounds__(256)
void prep128(const float* __restrict__ src, __hip_bfloat16* __restrict__ dst) {
  __shared__ __hip_bfloat16 tile[128][72];
  const int tid = threadIdx.x;
  const int c = blockIdx.x & 7, t = blockIdx.x >> 3;
  const float* srow = src + (size_t)t * 128 * D;
  __hip_bfloat16* dbase = dst + (size_t)t * BTILEG;

#pragma unroll
  for (int j = 0; j < 4; ++j) {
    int f = tid + j * 256;                 // 1024 granules: row = f>>3, k16l = f&7
    int row = f >> 3, k16l = f & 7;
    const float4* p = (const float4*)(srow + (size_t)row * D + c * 64 + k16l * 8);
    float4 v0 = p[0], v1 = p[1];
    float vv[8] = {v0.x, v0.y, v0.z, v0.w, v1.x, v1.y, v1.z, v1.w};
    union { bf16x8 v; unsigned short u[8]; } pk;
#pragma unroll
    for (int e = 0; e < 8; ++e) {
      __hip_bfloat16 h = __float2bfloat16(vv[e]);
      pk.u[e] = *(unsigned short*)&h;
    }
    *(bf16x8*)&tile[row][k16l * 8] = pk.v;
  }
  __syncthreads();
#pragma unroll
  for (int j = 0; j < 4; ++j) {
    int g = tid + j * 256;                 // row = g&127, k16l = g>>7
    int row = g & 127, k16l = g >> 7;
    bf16x8 v = *(const bf16x8*)&tile[row][k16l * 8];
    *(bf16x8*)(dbase + ((size_t)(c * 8 + k16l) * 128 + row) * 8) = v;
  }
}

// ---- 2. exact f32 row sum-of-squares (codebook) -----------------------------
__global__ __launch_bounds__(256)
void rowsumsq(const float* __restrict__ src, float* __restrict__ dst, int nrows) {
  int gw = (blockIdx.x * 256 + threadIdx.x) >> 6;
  if (gw >= nrows) return;
  int lane = threadIdx.x & 63;
  const float4* s4 = (const float4*)(src + (size_t)gw * D);
  float s = 0.f;
#pragma unroll
  for (int i = 0; i < 2; ++i) {
    float4 v = s4[lane + i * 64];
    s += v.x * v.x + v.y * v.y + v.z * v.z + v.w * v.w;
  }
#pragma unroll
  for (int off = 32; off > 0; off >>= 1) s += __shfl_down(s, off, 64);
  if (lane == 0) dst[gw] = s;
}

// ---- 3. 256x128-tile BK=64 GEMM, register-staged 2-phase dbuf ---------------
// 512 threads = 8 waves (wr 0..3 x wc 0..1). Wave tile: 64 rows x 64 codes.
// Swapped mfma(b, a): acc[nc][m][q] -> code = ct*128 + wc*64 + nc*16 + lh*4+q,
// row = mt*256 + wr*64 + m*16 + lr.
__global__ __launch_bounds__(512, 1)
void vq_gemm_rs(const __hip_bfloat16* __restrict__ Apack,
                const __hip_bfloat16* __restrict__ Bpack,
                const float* __restrict__ e_sq,
                ulonglong2* __restrict__ cand2) {
  extern __shared__ __hip_bfloat16 smem[];
  // granule map: buf*3072 + {A: 0..2047, B: 2048..3071}; 2 bufs = 96 KB

  const int tid = threadIdx.x;
  const int w = tid >> 6, l = tid & 63;
  const int wr = w >> 1, wc = w & 1;
  const int lr = l & 15, lh = l >> 4;

  const int bid = blockIdx.x;
  const int xcd = bid & 7, idx = bid >> 3;   // 512 blocks per XCD slot-space
  const int mt = xcd * 8 + (idx & 7);        // 64 m-tiles
  const int ct = idx >> 3;                   // 64 c-tiles

  const __hip_bfloat16* Abase = Apack + (size_t)mt * ATILEG;
  const __hip_bfloat16* Bbase = Bpack + (size_t)ct * BTILEG;

  f32x4 acc[4][4] = {};
  float4 rA[4], rB[2];

#define LOADR(t)                                                               \
  do {                                                                         \
    _Pragma("unroll")                                                          \
    for (int i = 0; i < 4; ++i)                                                \
      rA[i] = *(const float4*)(Abase + ((size_t)(t) * 2048 + tid + i * 512) * 8); \
    _Pragma("unroll")                                                          \
    for (int i = 0; i < 2; ++i)                                                \
      rB[i] = *(const float4*)(Bbase + ((size_t)(t) * 1024 + tid + i * 512) * 8); \
  } while (0)

#define WRITE(buf)                                                             \
  do {                                                                         \
    float4* Aw = (float4*)smem + (buf) * 3072;                                 \
    float4* Bw = Aw + 2048;                                                    \
    _Pragma("unroll")                                                          \
    for (int i = 0; i < 4; ++i) Aw[tid + i * 512] = rA[i];                     \
    _Pragma("unroll")                                                          \
    for (int i = 0; i < 2; ++i) Bw[tid + i * 512] = rB[i];                     \
  } while (0)

#define COMPUTE(buf)                                                           \
  do {                                                                         \
    const bf16x8* Ag = (const bf16x8*)smem + (buf) * 3072;                     \
    const bf16x8* Bg = Ag + 2048;                                              \
    _Pragma("unroll")                                                          \
    for (int kk = 0; kk < 2; ++kk) {                                           \
      const int kb = kk * 4 + lh;                                              \
      bf16x8 a[4], b[4];                                                       \
      _Pragma("unroll")                                                        \
      for (int nc = 0; nc < 4; ++nc) b[nc] = Bg[kb * 128 + wc * 64 + nc * 16 + lr]; \
      _Pragma("unroll")                                                        \
      for (int m = 0; m < 4; ++m)   a[m] = Ag[kb * 256 + wr * 64 + m * 16 + lr];    \
      _Pragma("unroll")                                                        \
      for (int nc = 0; nc < 4; ++nc)                                           \
        _Pragma("unroll")                                                      \
        for (int m = 0; m < 4; ++m)                                            \
          acc[nc][m] = __builtin_amdgcn_mfma_f32_16x16x32_bf16(b[nc], a[m],    \
                                                               acc[nc][m], 0, 0, 0); \
    }                                                                          \
  } while (0)

  LOADR(0);
  WRITE(0);
  __syncthreads();

#pragma unroll 1
  for (int t = 0; t < NSTEP - 1; ++t) {
    LOADR(t + 1);                // issue loads early: latency hides under MFMA
    COMPUTE(t & 1);
    WRITE((t + 1) & 1);          // vmcnt wait lands here, after compute
    __syncthreads();             // one barrier/step
  }
  COMPUTE((NSTEP - 1) & 1);
#undef LOADR
#undef WRITE
#undef COMPUTE

  // ---- epilogue: per-row top-2 keys over this wave's 64-code strip ----
  const int col0 = ct * 128 + wc * 64;
  float es[4][4];
#pragma unroll
  for (int nc = 0; nc < 4; ++nc) {
    float4 e4 = *(const float4*)&e_sq[col0 + nc * 16 + lh * 4];
    es[nc][0] = e4.x; es[nc][1] = e4.y; es[nc][2] = e4.z; es[nc][3] = e4.w;
  }
#pragma unroll
  for (int m = 0; m < 4; ++m) {
    unsigned long long k1 = KMAX, k2 = KMAX;
#pragma unroll
    for (int nc = 0; nc < 4; ++nc)
#pragma unroll
      for (int q = 0; q < 4; ++q) {
        int code = col0 + nc * 16 + lh * 4 + q;
        kins2(score_key(es[nc][q] - 2.0f * acc[nc][m][q], code), k1, k2);
      }
#pragma unroll
    for (int s = 16; s <= 32; s <<= 1) {     // reduce over lh
      unsigned long long o1 = __shfl_xor(k1, s, 64);
      unsigned long long o2 = __shfl_xor(k2, s, 64);
      kins2(o1, k1, k2);
      kins2(o2, k1, k2);
    }
    if (lh == 0) {
      int gRow = mt * 256 + wr * 64 + m * 16 + lr;
      cand2[(size_t)gRow * 128 + ct * 2 + wc] = make_ulonglong2(k1, k2);
    }
  }
}

// ---- 4. global top-4 over 256 keys/row, exact f32 rescore, gather -----------
__global__ __launch_bounds__(256)
void vq_merge4(const float* __restrict__ x, const float* __restrict__ cb,
               const float* __restrict__ values, const float* __restrict__ e_sq,
               const ulonglong2* __restrict__ cand2, float* __restrict__ out) {
  int row = blockIdx.x * 4 + (threadIdx.x >> 6);
  int l = threadIdx.x & 63;

  unsigned long long k0 = KMAX, k1 = KMAX, k2 = KMAX, k3 = KMAX;
  const ulonglong2* base = cand2 + (size_t)row * 128;
#pragma unroll
  for (int u = 0; u < 2; ++u) {
    ulonglong2 e = base[l + 64 * u];
    kins4(e.x, k0, k1, k2, k3);
    kins4(e.y, k0, k1, k2, k3);
  }
#pragma unroll
  for (int s = 1; s < 64; s <<= 1) {
    unsigned long long o0 = __shfl_xor(k0, s, 64), o1 = __shfl_xor(k1, s, 64);
    unsigned long long o2 = __shfl_xor(k2, s, 64), o3 = __shfl_xor(k3, s, 64);
    kins4(o0, k0, k1, k2, k3); kins4(o1, k0, k1, k2, k3);
    kins4(o2, k0, k1, k2, k3); kins4(o3, k0, k1, k2, k3);
  }
  int i0 = (int)(k0 & 8191), i1 = (int)(k1 & 8191);
  int i2 = (int)(k2 & 8191), i3 = (int)(k3 & 8191);

  // exact f32 rescore (deterministic order)
  const float4* xr = (const float4*)(x + (size_t)row * D);
  const float4* c0 = (const float4*)(cb + (size_t)i0 * D);
  const float4* c1 = (const float4*)(cb + (size_t)i1 * D);
  const float4* c2 = (const float4*)(cb + (size_t)i2 * D);
  const float4* c3 = (const float4*)(cb + (size_t)i3 * D);
  float xsq = 0.f, t0 = 0.f, t1 = 0.f, t2 = 0.f, t3 = 0.f;
#pragma unroll
  for (int u = 0; u < 2; ++u) {
    float4 xv = xr[l + 64 * u];
    float4 a = c0[l + 64 * u], b = c1[l + 64 * u];
    float4 c = c2[l + 64 * u], e = c3[l + 64 * u];
    xsq += xv.x * xv.x + xv.y * xv.y + xv.z * xv.z + xv.w * xv.w;
    t0 += xv.x * a.x + xv.y * a.y + xv.z * a.z + xv.w * a.w;
    t1 += xv.x * b.x + xv.y * b.y + xv.z * b.z + xv.w * b.w;
    t2 += xv.x * c.x + xv.y * c.y + xv.z * c.z + xv.w * c.w;
    t3 += xv.x * e.x + xv.y * e.y + xv.z * e.z + xv.w * e.w;
  }
#pragma unroll
  for (int s = 1; s < 64; s <<= 1) {
    xsq += __shfl_xor(xsq, s, 64);
    t0 += __shfl_xor(t0, s, 64); t1 += __shfl_xor(t1, s, 64);
    t2 += __shfl_xor(t2, s, 64); t3 += __shfl_xor(t3, s, 64);
  }
  float D0 = xsq - 2.0f * t0 + e_sq[i0];
  float D1 = xsq - 2.0f * t1 + e_sq[i1];
  float D2 = xsq - 2.0f * t2 + e_sq[i2];
  float D3 = xsq - 2.0f * t3 + e_sq[i3];
  float bdist = D0; int best = i0;
  if (D1 < bdist || (D1 == bdist && i1 < best)) { bdist = D1; best = i1; }
  if (D2 < bdist || (D2 == bdist && i2 < best)) { bdist = D2; best = i2; }
  if (D3 < bdist || (D3 == bdist && i3 < best)) { bdist = D3; best = i3; }

  const float4* vsrc = (const float4*)(values + (size_t)best * D);
  float4* dst = (float4*)(out + (size_t)row * D);
  dst[l] = vsrc[l];
  dst[l + 64] = vsrc[l + 64];
}

// ============================================================================
extern "C" void kernel_launch(void* const* d_in, const int* in_sizes, int n_in,
                              void* d_out, int out_size, void* d_ws, size_t ws_size,
                              hipStream_t stream) {
  const float* x      = (const float*)d_in[0];
  const float* cb     = (const float*)d_in[1];
  const float* values = (const float*)d_in[2];
  float* out = (float*)d_out;

  const size_t A_BYTES = (size_t)M * 512 * 2;         // 16 MB
  const size_t B_BYTES = (size_t)NCODE * 512 * 2;     // 8 MB
  const size_t C_BYTES = (size_t)M * 128 * 16;        // 32 MB (key pairs)

  char* base = (char*)d_ws;
  __hip_bfloat16* Apack = (__hip_bfloat16*)base;
  __hip_bfloat16* Bpack = (__hip_bfloat16*)(base + A_BYTES);
  ulonglong2* cand2 = (ulonglong2*)(base + A_BYTES + B_BYTES);
  float* e_sq = (float*)(base + A_BYTES + B_BYTES + C_BYTES);

  const int LDS_GEMM = 98304;   // 2 x (32 KB A + 16 KB B)
  (void)hipFuncSetAttribute(reinterpret_cast<const void*>(vq_gemm_rs),
                            hipFuncAttributeMaxDynamicSharedMemorySize, LDS_GEMM);

  prep256<<<(M / 256) * 8, 256, 0, stream>>>(x, Apack);
  prep128<<<(NCODE / 128) * 8, 256, 0, stream>>>(cb, Bpack);
  rowsumsq<<<NCODE / 4, 256, 0, stream>>>(cb, e_sq, NCODE);
  vq_gemm_rs<<<(M / 256) * (NCODE / 128), 512, LDS_GEMM, stream>>>(
      Apack, Bpack, e_sq, cand2);
  vq_merge4<<<M / 4, 256, 0, stream>>>(x, cb, values, e_sq, cand2, out);
}

// Round 9
// 798.047 us; speedup vs baseline: 1.0222x; 1.0222x over previous
//
#include <hip/hip_runtime.h>
#include <hip/hip_bf16.h>

// VectorQuantize: argmin_k ||x - e_k||^2 then gather values[k].
// R9: 256x128-tile GEMM with TWO independent 4-wave blocks per CU
// (2 waves/SIMD, one from each block -> barrier drains interleave across
// blocks; R1-R8 analysis shows all variants pinned at ~2 TB/s operand read
// with per-byte rate tracking blocks/CU). BK=32, static 48 KB LDS dbuf,
// gload_lds staging, one barrier/step. Epilogue: per-wave top-2 keys per
// 64-code strip -> global top-4 -> exact f32 rescore (np tie semantics)
// -> gather values[best].
//
// Pack layouts (granule = 8 bf16 = 16 B):
//   Apack[64 tiles][k16 0..63][row 0..255][8]   A slab/step(BK=32): 1024 g
//   Bpack[64 tiles][k16 0..63][row 0..127][8]   B slab/step: 512 g

#define D      512
#define M      16384
#define NCODE  8192
#define NSTEP  16          // K=512 / BK=32
#define ATILEG 131072      // elems per A tile (256*512)
#define BTILEG 65536       // elems per B tile (128*512)

typedef float f32x4  __attribute__((ext_vector_type(4)));
typedef short bf16x8 __attribute__((ext_vector_type(8)));

#define KMAX 0xFFFFFFFFFFFFFFFFull

__device__ __forceinline__ void gload16(const __hip_bfloat16* g, __hip_bfloat16* l) {
  __builtin_amdgcn_global_load_lds(
      (const __attribute__((address_space(1))) void*)g,
      (__attribute__((address_space(3))) void*)l, 16, 0, 0);
}

__device__ __forceinline__ unsigned long long score_key(float sc, int code) {
  unsigned int u = __float_as_uint(sc);
  unsigned int su = u ^ ((unsigned int)((int)u >> 31) | 0x80000000u);
  return ((unsigned long long)su << 32) | (unsigned int)code;
}

__device__ __forceinline__ void kins2(unsigned long long k,
                                      unsigned long long& k1, unsigned long long& k2) {
  if (k < k1) { k2 = k1; k1 = k; }
  else if (k < k2) { k2 = k; }
}

__device__ __forceinline__ void kins4(unsigned long long k,
    unsigned long long& k0, unsigned long long& k1,
    unsigned long long& k2, unsigned long long& k3) {
  if (k < k0)      { k3 = k2; k2 = k1; k1 = k0; k0 = k; }
  else if (k < k1) { k3 = k2; k2 = k1; k1 = k; }
  else if (k < k2) { k3 = k2; k2 = k; }
  else if (k < k3) { k3 = k; }
}

// ---- 1a. f32 -> hi-bf16 256-row tile-transposed pack ------------------------
__global__ __launch_bounds__(256)
void prep256(const float* __restrict__ src, __hip_bfloat16* __restrict__ dst) {
  __shared__ __hip_bfloat16 tile[256][72];
  const int tid = threadIdx.x;
  const int c = blockIdx.x & 7, t = blockIdx.x >> 3;
  const float* srow = src + (size_t)t * 256 * D;
  __hip_bfloat16* dbase = dst + (size_t)t * ATILEG;

#pragma unroll
  for (int j = 0; j < 8; ++j) {
    int f = tid + j * 256;                 // row = f>>3, k16l = f&7
    int row = f >> 3, k16l = f & 7;
    const float4* p = (const float4*)(srow + (size_t)row * D + c * 64 + k16l * 8);
    float4 v0 = p[0], v1 = p[1];
    float vv[8] = {v0.x, v0.y, v0.z, v0.w, v1.x, v1.y, v1.z, v1.w};
    union { bf16x8 v; unsigned short u[8]; } pk;
#pragma unroll
    for (int e = 0; e < 8; ++e) {
      __hip_bfloat16 h = __float2bfloat16(vv[e]);   // RNE
      pk.u[e] = *(unsigned short*)&h;
    }
    *(bf16x8*)&tile[row][k16l * 8] = pk.v;
  }
  __syncthreads();
#pragma unroll
  for (int j = 0; j < 8; ++j) {
    int g = tid + j * 256;                 // row = g&255, k16l = g>>8
    int row = g & 255, k16l = g >> 8;
    bf16x8 v = *(const bf16x8*)&tile[row][k16l * 8];
    *(bf16x8*)(dbase + ((size_t)(c * 8 + k16l) * 256 + row) * 8) = v;
  }
}

// ---- 1b. f32 -> hi-bf16 128-row tile-transposed pack ------------------------
__global__ __launch_bounds__(256)
void prep128(const float* __restrict__ src, __hip_bfloat16* __restrict__ dst) {
  __shared__ __hip_bfloat16 tile[128][72];
  const int tid = threadIdx.x;
  const int c = blockIdx.x & 7, t = blockIdx.x >> 3;
  const float* srow = src + (size_t)t * 128 * D;
  __hip_bfloat16* dbase = dst + (size_t)t * BTILEG;

#pragma unroll
  for (int j = 0; j < 4; ++j) {
    int f = tid + j * 256;                 // row = f>>3, k16l = f&7
    int row = f >> 3, k16l = f & 7;
    const float4* p = (const float4*)(srow + (size_t)row * D + c * 64 + k16l * 8);
    float4 v0 = p[0], v1 = p[1];
    float vv[8] = {v0.x, v0.y, v0.z, v0.w, v1.x, v1.y, v1.z, v1.w};
    union { bf16x8 v; unsigned short u[8]; } pk;
#pragma unroll
    for (int e = 0; e < 8; ++e) {
      __hip_bfloat16 h = __float2bfloat16(vv[e]);
      pk.u[e] = *(unsigned short*)&h;
    }
    *(bf16x8*)&tile[row][k16l * 8] = pk.v;
  }
  __syncthreads();
#pragma unroll
  for (int j = 0; j < 4; ++j) {
    int g = tid + j * 256;                 // row = g&127, k16l = g>>7
    int row = g & 127, k16l = g >> 7;
    bf16x8 v = *(const bf16x8*)&tile[row][k16l * 8];
    *(bf16x8*)(dbase + ((size_t)(c * 8 + k16l) * 128 + row) * 8) = v;
  }
}

// ---- 2. exact f32 row sum-of-squares (codebook) -----------------------------
__global__ __launch_bounds__(256)
void rowsumsq(const float* __restrict__ src, float* __restrict__ dst, int nrows) {
  int gw = (blockIdx.x * 256 + threadIdx.x) >> 6;
  if (gw >= nrows) return;
  int lane = threadIdx.x & 63;
  const float4* s4 = (const float4*)(src + (size_t)gw * D);
  float s = 0.f;
#pragma unroll
  for (int i = 0; i < 2; ++i) {
    float4 v = s4[lane + i * 64];
    s += v.x * v.x + v.y * v.y + v.z * v.z + v.w * v.w;
  }
#pragma unroll
  for (int off = 32; off > 0; off >>= 1) s += __shfl_down(s, off, 64);
  if (lane == 0) dst[gw] = s;
}

// ---- 3. 256x128-tile BK=32 GEMM, 2 blocks/CU, 2-phase dbuf ------------------
// 256 threads = 4 waves (wr 0..1 x wc 0..1). Wave tile: 128 rows x 64 codes.
// Swapped mfma(b, a): acc[nc][m][q] -> code = ct*128 + wc*64 + nc*16 + lh*4+q,
// row = mt*256 + wr*128 + m*16 + lr.
__global__ __launch_bounds__(256, 2)
void vq_gemm2b(const __hip_bfloat16* __restrict__ Apack,
               const __hip_bfloat16* __restrict__ Bpack,
               const float* __restrict__ e_sq,
               ulonglong2* __restrict__ cand2) {
  __shared__ __hip_bfloat16 As[2][1024 * 8];   // 2 x 16 KB
  __shared__ __hip_bfloat16 Bs[2][512 * 8];    // 2 x 8 KB

  const int tid = threadIdx.x;
  const int w = tid >> 6, l = tid & 63;
  const int wr = w >> 1, wc = w & 1;
  const int lr = l & 15, lh = l >> 4;

  const int bid = blockIdx.x;
  const int xcd = bid & 7, idx = bid >> 3;   // 512 blocks per XCD
  const int mt = xcd * 8 + (idx & 7);        // 64 m-tiles (L2-resident stripe)
  const int ct = idx >> 3;                   // 64 c-tiles (slow sweep)

  const __hip_bfloat16* Abase = Apack + (size_t)mt * ATILEG;
  const __hip_bfloat16* Bbase = Bpack + (size_t)ct * BTILEG;

  f32x4 acc[4][8] = {};

#define STAGE(buf, t)                                                          \
  do {                                                                         \
    _Pragma("unroll")                                                          \
    for (int i = 0; i < 4; ++i)                                                \
      gload16(Abase + ((size_t)(t) * 1024 + tid + i * 256) * 8,                \
              As[(buf)] + (size_t)(tid + i * 256) * 8);                        \
    _Pragma("unroll")                                                          \
    for (int i = 0; i < 2; ++i)                                                \
      gload16(Bbase + ((size_t)(t) * 512 + tid + i * 256) * 8,                 \
              Bs[(buf)] + (size_t)(tid + i * 256) * 8);                        \
  } while (0)

#define COMPUTE(buf)                                                           \
  do {                                                                         \
    const bf16x8* Ag = (const bf16x8*)As[(buf)];                               \
    const bf16x8* Bg = (const bf16x8*)Bs[(buf)];                               \
    const int kb = lh;                                                         \
    bf16x8 a[8], b[4];                                                         \
    _Pragma("unroll")                                                          \
    for (int nc = 0; nc < 4; ++nc) b[nc] = Bg[kb * 128 + wc * 64 + nc * 16 + lr]; \
    _Pragma("unroll")                                                          \
    for (int m = 0; m < 8; ++m)   a[m] = Ag[kb * 256 + wr * 128 + m * 16 + lr];   \
    _Pragma("unroll")                                                          \
    for (int nc = 0; nc < 4; ++nc)                                             \
      _Pragma("unroll")                                                        \
      for (int m = 0; m < 8; ++m)                                              \
        acc[nc][m] = __builtin_amdgcn_mfma_f32_16x16x32_bf16(b[nc], a[m],      \
                                                             acc[nc][m], 0, 0, 0); \
  } while (0)

  STAGE(0, 0);
  __syncthreads();

#pragma unroll 1
  for (int t = 0; t < NSTEP - 1; ++t) {
    const int cur = t & 1;
    STAGE(cur ^ 1, t + 1);       // prefetch issued before compute
    COMPUTE(cur);
    __syncthreads();             // one barrier per step
  }
  COMPUTE((NSTEP - 1) & 1);
#undef STAGE
#undef COMPUTE

  // ---- epilogue: per-row top-2 keys over this wave's 64-code strip ----
  const int col0 = ct * 128 + wc * 64;
  float es[4][4];
#pragma unroll
  for (int nc = 0; nc < 4; ++nc) {
    float4 e4 = *(const float4*)&e_sq[col0 + nc * 16 + lh * 4];
    es[nc][0] = e4.x; es[nc][1] = e4.y; es[nc][2] = e4.z; es[nc][3] = e4.w;
  }
#pragma unroll
  for (int m = 0; m < 8; ++m) {
    unsigned long long k1 = KMAX, k2 = KMAX;
#pragma unroll
    for (int nc = 0; nc < 4; ++nc)
#pragma unroll
      for (int q = 0; q < 4; ++q) {
        int code = col0 + nc * 16 + lh * 4 + q;
        kins2(score_key(es[nc][q] - 2.0f * acc[nc][m][q], code), k1, k2);
      }
#pragma unroll
    for (int s = 16; s <= 32; s <<= 1) {     // reduce over lh
      unsigned long long o1 = __shfl_xor(k1, s, 64);
      unsigned long long o2 = __shfl_xor(k2, s, 64);
      kins2(o1, k1, k2);
      kins2(o2, k1, k2);
    }
    if (lh == 0) {
      int gRow = mt * 256 + wr * 128 + m * 16 + lr;
      cand2[(size_t)gRow * 128 + ct * 2 + wc] = make_ulonglong2(k1, k2);
    }
  }
}

// ---- 4. global top-4 over 256 keys/row, exact f32 rescore, gather -----------
__global__ __launch_bounds__(256)
void vq_merge4(const float* __restrict__ x, const float* __restrict__ cb,
               const float* __restrict__ values, const float* __restrict__ e_sq,
               const ulonglong2* __restrict__ cand2, float* __restrict__ out) {
  int row = blockIdx.x * 4 + (threadIdx.x >> 6);
  int l = threadIdx.x & 63;

  unsigned long long k0 = KMAX, k1 = KMAX, k2 = KMAX, k3 = KMAX;
  const ulonglong2* base = cand2 + (size_t)row * 128;
#pragma unroll
  for (int u = 0; u < 2; ++u) {
    ulonglong2 e = base[l + 64 * u];
    kins4(e.x, k0, k1, k2, k3);
    kins4(e.y, k0, k1, k2, k3);
  }
#pragma unroll
  for (int s = 1; s < 64; s <<= 1) {
    unsigned long long o0 = __shfl_xor(k0, s, 64), o1 = __shfl_xor(k1, s, 64);
    unsigned long long o2 = __shfl_xor(k2, s, 64), o3 = __shfl_xor(k3, s, 64);
    kins4(o0, k0, k1, k2, k3); kins4(o1, k0, k1, k2, k3);
    kins4(o2, k0, k1, k2, k3); kins4(o3, k0, k1, k2, k3);
  }
  int i0 = (int)(k0 & 8191), i1 = (int)(k1 & 8191);
  int i2 = (int)(k2 & 8191), i3 = (int)(k3 & 8191);

  // exact f32 rescore (deterministic order)
  const float4* xr = (const float4*)(x + (size_t)row * D);
  const float4* c0 = (const float4*)(cb + (size_t)i0 * D);
  const float4* c1 = (const float4*)(cb + (size_t)i1 * D);
  const float4* c2 = (const float4*)(cb + (size_t)i2 * D);
  const float4* c3 = (const float4*)(cb + (size_t)i3 * D);
  float xsq = 0.f, t0 = 0.f, t1 = 0.f, t2 = 0.f, t3 = 0.f;
#pragma unroll
  for (int u = 0; u < 2; ++u) {
    float4 xv = xr[l + 64 * u];
    float4 a = c0[l + 64 * u], b = c1[l + 64 * u];
    float4 c = c2[l + 64 * u], e = c3[l + 64 * u];
    xsq += xv.x * xv.x + xv.y * xv.y + xv.z * xv.z + xv.w * xv.w;
    t0 += xv.x * a.x + xv.y * a.y + xv.z * a.z + xv.w * a.w;
    t1 += xv.x * b.x + xv.y * b.y + xv.z * b.z + xv.w * b.w;
    t2 += xv.x * c.x + xv.y * c.y + xv.z * c.z + xv.w * c.w;
    t3 += xv.x * e.x + xv.y * e.y + xv.z * e.z + xv.w * e.w;
  }
#pragma unroll
  for (int s = 1; s < 64; s <<= 1) {
    xsq += __shfl_xor(xsq, s, 64);
    t0 += __shfl_xor(t0, s, 64); t1 += __shfl_xor(t1, s, 64);
    t2 += __shfl_xor(t2, s, 64); t3 += __shfl_xor(t3, s, 64);
  }
  float D0 = xsq - 2.0f * t0 + e_sq[i0];
  float D1 = xsq - 2.0f * t1 + e_sq[i1];
  float D2 = xsq - 2.0f * t2 + e_sq[i2];
  float D3 = xsq - 2.0f * t3 + e_sq[i3];
  float bdist = D0; int best = i0;
  if (D1 < bdist || (D1 == bdist && i1 < best)) { bdist = D1; best = i1; }
  if (D2 < bdist || (D2 == bdist && i2 < best)) { bdist = D2; best = i2; }
  if (D3 < bdist || (D3 == bdist && i3 < best)) { bdist = D3; best = i3; }

  const float4* vsrc = (const float4*)(values + (size_t)best * D);
  float4* dst = (float4*)(out + (size_t)row * D);
  dst[l] = vsrc[l];
  dst[l + 64] = vsrc[l + 64];
}

// ============================================================================
extern "C" void kernel_launch(void* const* d_in, const int* in_sizes, int n_in,
                              void* d_out, int out_size, void* d_ws, size_t ws_size,
                              hipStream_t stream) {
  const float* x      = (const float*)d_in[0];
  const float* cb     = (const float*)d_in[1];
  const float* values = (const float*)d_in[2];
  float* out = (float*)d_out;

  const size_t A_BYTES = (size_t)M * 512 * 2;         // 16 MB
  const size_t B_BYTES = (size_t)NCODE * 512 * 2;     // 8 MB
  const size_t C_BYTES = (size_t)M * 128 * 16;        // 32 MB (key pairs)

  char* base = (char*)d_ws;
  __hip_bfloat16* Apack = (__hip_bfloat16*)base;
  __hip_bfloat16* Bpack = (__hip_bfloat16*)(base + A_BYTES);
  ulonglong2* cand2 = (ulonglong2*)(base + A_BYTES + B_BYTES);
  float* e_sq = (float*)(base + A_BYTES + B_BYTES + C_BYTES);

  prep256<<<(M / 256) * 8, 256, 0, stream>>>(x, Apack);
  prep128<<<(NCODE / 128) * 8, 256, 0, stream>>>(cb, Bpack);
  rowsumsq<<<NCODE / 4, 256, 0, stream>>>(cb, e_sq, NCODE);
  vq_gemm2b<<<(M / 256) * (NCODE / 128), 256, 0, stream>>>(
      Apack, Bpack, e_sq, cand2);
  vq_merge4<<<M / 4, 256, 0, stream>>>(x, cb, values, e_sq, cand2, out);
}